// Round 7
// baseline (350.537 us; speedup 1.0000x reference)
//
#include <hip/hip_runtime.h>
#include <hip/hip_bf16.h>

#define HSEQ 16777216   // 512*32*1024
#define NH 1024

typedef __attribute__((ext_vector_type(8))) short bf16x8;
typedef __attribute__((ext_vector_type(4))) float f32x4;

__device__ __forceinline__ unsigned short f2bf(float f) {
  unsigned u = __builtin_bit_cast(unsigned, f);
  u += 0x7fffu + ((u >> 16) & 1u);
  return (unsigned short)(u >> 16);
}

__device__ __forceinline__ float fsig(float z) {   // 1/(1+e^-z)
  float e = __builtin_amdgcn_exp2f(-1.442695041f * z);
  return __builtin_amdgcn_rcpf(1.f + e);
}
__device__ __forceinline__ float ftanh(float z) {  // 1 - 2/(e^{2z}+1)
  float e = __builtin_amdgcn_exp2f(2.885390082f * z);
  return 1.f - 2.f * __builtin_amdgcn_rcpf(1.f + e);
}

// One launch: blocks 0-3071 convert x + 4 input-weights fp32->bf16;
// blocks 3072-3583 compute hz[g][b][h] = h0·w_h^T + b_i + b_h.
__global__ __launch_bounds__(256) void cvt_hz(
    const float* __restrict__ x,
    const float* __restrict__ wi, const float* __restrict__ wf,
    const float* __restrict__ wo, const float* __restrict__ wg,
    unsigned short* __restrict__ xb, unsigned short* __restrict__ wb,
    const float* __restrict__ h0,
    const float* __restrict__ wh_i, const float* __restrict__ wh_f,
    const float* __restrict__ wh_o, const float* __restrict__ wh_g,
    const float* __restrict__ bi_i, const float* __restrict__ bh_i,
    const float* __restrict__ bi_f, const float* __restrict__ bh_f,
    const float* __restrict__ bi_o, const float* __restrict__ bh_o,
    const float* __restrict__ bi_g, const float* __restrict__ bh_g,
    float* __restrict__ hz) {
  int bid = blockIdx.x;
  int tid = threadIdx.x;
  if (bid < 3072) {
    const float* src; unsigned short* dst; int base, iters;
    if (bid < 2048) {
      src = x; dst = xb; base = bid * 8192; iters = 8;
    } else {
      int g = bid - 2048; int ws = g >> 8; int blk = g & 255;
      src = (ws == 0) ? wi : (ws == 1) ? wf : (ws == 2) ? wo : wg;
      dst = wb + ws * 1048576; base = blk * 4096; iters = 4;
    }
    for (int i = 0; i < iters; ++i) {
      int idx = base + i * 1024 + tid * 4;
      float4 v = *reinterpret_cast<const float4*>(src + idx);
      ushort4 o;
      o.x = f2bf(v.x); o.y = f2bf(v.y); o.z = f2bf(v.z); o.w = f2bf(v.w);
      *reinterpret_cast<ushort4*>(dst + idx) = o;
    }
  } else {
    __shared__ float ws[8 * 1024];
    int hbid = bid - 3072;               // 0..511
    int g = hbid >> 7;
    int hb = hbid & 127;
    const float* wh = (g == 0) ? wh_i : (g == 1) ? wh_f : (g == 2) ? wh_o : wh_g;
    const float* bi = (g == 0) ? bi_i : (g == 1) ? bi_f : (g == 2) ? bi_o : bi_g;
    const float* bh = (g == 0) ? bh_i : (g == 1) ? bh_f : (g == 2) ? bh_o : bh_g;
    const float4* wsrc = reinterpret_cast<const float4*>(wh + hb * 8 * 1024);
    float4* wdst = reinterpret_cast<float4*>(ws);
    for (int i = tid; i < 2048; i += 256) wdst[i] = wsrc[i];
    __syncthreads();
    int b = tid & 31;
    int hh = tid >> 5;
    const float4* hv = reinterpret_cast<const float4*>(h0 + b * NH);
    const float4* wv = reinterpret_cast<const float4*>(ws + hh * NH);
    float acc = 0.f;
    for (int k = 0; k < 256; ++k) {
      float4 a = hv[k], w4 = wv[k];
      acc += a.x * w4.x + a.y * w4.y + a.z * w4.z + a.w * w4.w;
    }
    int h = hb * 8 + hh;
    hz[g * (32 * NH) + b * NH + h] = acc + bi[h] + bh[h];
  }
}

__device__ __forceinline__ void load_lds16(const void* gsrc, void* lds) {
  __builtin_amdgcn_global_load_lds(
      (const __attribute__((address_space(1))) unsigned int*)gsrc,
      (__attribute__((address_space(3))) unsigned int*)lds, 16, 0, 0);
}

// Persistent 256x256 8-phase GEMM, 1 block/CU, grid=256, ONE dispatch round.
// XCD x (= bid&7) owns ht in {2x,2x+1} (B-slice 1MB, L2-resident); its 16
// slots give mt = slot + 16*mw, mw=0..3 -> 32 seamless K-iters per block.
// Per-iter schedule is byte-identical to the round-5 audited version
// (register-double-buffered fragments, 1 stage unit/phase, VM(4)@p2/p6).
__global__ __launch_bounds__(512, 2) void lstm_gemm8(
    const unsigned short* __restrict__ xb,   // [16384][1024] bf16
    const unsigned short* __restrict__ wb,   // [4][1024][1024] bf16 (i,f,o,g)
    const float* __restrict__ hz,            // [4][32][1024] f32
    const float* __restrict__ c0,            // [32][1024] f32
    float* __restrict__ out) {
  __shared__ unsigned short As[2][16384];    // [buf][256 rows][64 cols]
  __shared__ unsigned short Bs[2][16384];

  const int bid = blockIdx.x;                // 256 blocks
  const int xcd = bid & 7;
  const int i32 = bid >> 3;                  // 0..31
  const int ht = xcd * 2 + (i32 & 1);        // 0..15
  const int msl = i32 >> 1;                  // slot 0..15
  const int hBase = ht * 64;

  const int tid = threadIdx.x;
  const int lane = tid & 63;
  const int w = tid >> 6;
  const int wr = w >> 2;        // 0..1
  const int wc = w & 3;         // 0..3
  const int laneLow = lane & 15;
  const int lane4 = lane >> 4;  // 0..3
  const int lx = lane & 7;

  const int sRow = w * 8 + (lane >> 3);               // row within 64-row round
  const int sCol = ((lane & 7) ^ (lane >> 3)) * 8;    // inverse-swizzled col
  const unsigned bOff = (unsigned)((hBase + sRow) * 1024 + sCol);

#define STAGE_A(buf, t, h)                                                         \
  do {                                                                             \
    unsigned tq_ = (unsigned)(t) >> 4, tr_ = (unsigned)(t) & 15;                   \
    _Pragma("unroll") for (int r_ = 0; r_ < 2; ++r_) {                             \
      unsigned row_ = (unsigned)(msl * 256) + tq_ * 4096 + (h) * 128 + r_ * 64 + sRow; \
      load_lds16(xb + (size_t)row_ * 1024 + tr_ * 64 + sCol,                       \
                 &As[buf][(h) * 8192 + r_ * 4096 + w * 512]);                      \
    }                                                                              \
  } while (0)

#define STAGE_B(buf, t, h)                                                         \
  do {                                                                             \
    unsigned tr_ = (unsigned)(t) & 15;                                             \
    _Pragma("unroll") for (int r_ = 0; r_ < 2; ++r_) {                             \
      load_lds16(wb + (size_t)((h) * 2 + r_) * 1048576 + bOff + tr_ * 64,          \
                 &Bs[buf][(h) * 8192 + r_ * 4096 + w * 512]);                      \
    }                                                                              \
  } while (0)

#define LDA(dst, buf, mh)                                                          \
  do {                                                                             \
    _Pragma("unroll") for (int mi = 0; mi < 4; ++mi)                               \
    _Pragma("unroll") for (int kk = 0; kk < 2; ++kk) {                             \
      int row_ = wr * 128 + (mh) * 64 + mi * 16 + laneLow;                         \
      int slot_ = (kk * 4 + lane4) ^ lx;                                           \
      dst[mi][kk] = *reinterpret_cast<const bf16x8*>(&As[buf][row_ * 64 + slot_ * 8]); \
    }                                                                              \
  } while (0)

#define LDB(dst, buf, qh)                                                          \
  do {                                                                             \
    _Pragma("unroll") for (int q = 0; q < 2; ++q)                                  \
    _Pragma("unroll") for (int kk = 0; kk < 2; ++kk) {                             \
      int row_ = ((qh) * 2 + q) * 64 + wc * 16 + laneLow;                          \
      int slot_ = (kk * 4 + lane4) ^ lx;                                           \
      dst[q][kk] = *reinterpret_cast<const bf16x8*>(&Bs[buf][row_ * 64 + slot_ * 8]); \
    }                                                                              \
  } while (0)

#define MFMA16(A, B, MH, QH)                                                       \
  do {                                                                             \
    __builtin_amdgcn_s_setprio(1);                                                 \
    _Pragma("unroll") for (int mi = 0; mi < 4; ++mi)                               \
    _Pragma("unroll") for (int q = 0; q < 2; ++q)                                  \
    _Pragma("unroll") for (int kk = 0; kk < 2; ++kk)                               \
      acc[(MH) * 4 + mi][(QH) * 2 + q] = __builtin_amdgcn_mfma_f32_16x16x32_bf16(  \
          A[mi][kk], B[q][kk], acc[(MH) * 4 + mi][(QH) * 2 + q], 0, 0, 0);         \
    __builtin_amdgcn_s_setprio(0);                                                 \
  } while (0)

#define BAR __builtin_amdgcn_s_barrier()
#define VM(n) asm volatile("s_waitcnt vmcnt(" #n ")" ::: "memory")

  f32x4 acc[8][4];
#pragma unroll
  for (int i = 0; i < 8; ++i)
#pragma unroll
    for (int jj = 0; jj < 4; ++jj) acc[i][jj] = (f32x4){0.f, 0.f, 0.f, 0.f};

  bf16x8 afX[4][2], afY[4][2], bqA[2][2], bqB[2][2];

  // Prologue: buf0 <- tile0 complete; buf1 <- tile1 (B0,B1,A0).
  STAGE_B(0, 0, 0); STAGE_B(0, 0, 1); STAGE_A(0, 0, 0); STAGE_A(0, 0, 1);
  STAGE_B(1, 1, 0); STAGE_B(1, 1, 1); STAGE_A(1, 1, 0);
  VM(0);
  BAR;
  LDB(bqA, 0, 0);
  LDA(afX, 0, 0);

  const int hOut = hBase + wc * 16 + laneLow;
  const int b00 = msl >> 1;

  for (int mw = 0; mw < 4; ++mw) {     // m-tile loop (dynamic)
#pragma unroll
    for (int it2 = 0; it2 < 8; ++it2) {
      const int base_t = 16 * mw + 2 * it2;
      const int tOdd = base_t + 1;
      const int tA2 = (base_t + 2 > 63) ? 63 : base_t + 2;
      const int tB2 = (base_t + 3 > 63) ? 63 : base_t + 3;

      // p0
      LDB(bqB, 0, 1);
      STAGE_A(1, tOdd, 1);
      MFMA16(afX, bqA, 0, 0);
      BAR;
      // p1
      LDA(afY, 0, 1);
      STAGE_B(0, tA2, 0);
      MFMA16(afX, bqB, 0, 1);
      BAR;
      // p2
      STAGE_B(0, tA2, 1);
      MFMA16(afY, bqB, 1, 1);
      VM(4);
      BAR;
      // p3
      LDB(bqB, 1, 0);
      LDA(afX, 1, 0);
      STAGE_A(0, tA2, 0);
      MFMA16(afY, bqA, 1, 0);
      BAR;
      // p4
      LDB(bqA, 1, 1);
      STAGE_A(0, tA2, 1);
      MFMA16(afX, bqB, 0, 0);
      BAR;
      // p5
      LDA(afY, 1, 1);
      STAGE_B(1, tB2, 0);
      MFMA16(afX, bqA, 0, 1);
      BAR;
      // p6
      STAGE_B(1, tB2, 1);
      MFMA16(afY, bqA, 1, 1);
      VM(4);
      BAR;
      // p7
      LDB(bqA, 0, 0);
      LDA(afX, 0, 0);
      STAGE_A(1, tB2, 0);
      MFMA16(afY, bqB, 1, 0);
      BAR;
    }

    // ---- epilogue for m-tile mw (register-only math + stores) ----
    {
      const int mB = (msl + 16 * mw) * 256;
      const int b = b00 + 8 * mw;
      const float hz0 = hz[0 * 32768 + b * 1024 + hOut];
      const float hz1 = hz[1 * 32768 + b * 1024 + hOut];
      const float hz2 = hz[2 * 32768 + b * 1024 + hOut];
      const float hz3 = hz[3 * 32768 + b * 1024 + hOut];
      const float c0v = c0[b * 1024 + hOut];
#pragma unroll
      for (int mi16 = 0; mi16 < 8; ++mi16) {
#pragma unroll
        for (int r = 0; r < 4; ++r) {
          int m = mB + wr * 128 + mi16 * 16 + lane4 * 4 + r;
          int ts = m & 511;
          float zi = acc[mi16][0][r] + hz0;
          float zf = acc[mi16][1][r] + hz1;
          float zo = acc[mi16][2][r] + hz2;
          float zg = acc[mi16][3][r] + hz3;
          float iv = fsig(zi);
          float fv = fsig(zf);
          float ov = fsig(zo);
          float gv = ftanh(zg);
          float cv = fv * c0v + iv * gv;
          float hval = ov * ftanh(cv);
          out[(size_t)ts * 32768 + b * 1024 + hOut] = hval;
          if (ts == 511) {
            out[HSEQ + b * 1024 + hOut] = hval;
            out[HSEQ + 32768 + b * 1024 + hOut] = cv;
          }
        }
      }
#pragma unroll
      for (int i = 0; i < 8; ++i)
#pragma unroll
        for (int jj = 0; jj < 4; ++jj) acc[i][jj] = (f32x4){0.f, 0.f, 0.f, 0.f};
    }
  }
}

extern "C" void kernel_launch(void* const* d_in, const int* in_sizes, int n_in,
                              void* d_out, int out_size, void* d_ws, size_t ws_size,
                              hipStream_t stream) {
  const float* x    = (const float*)d_in[0];
  const float* h0   = (const float*)d_in[1];
  const float* c0   = (const float*)d_in[2];
  const float* w_ii = (const float*)d_in[3];
  const float* b_ii = (const float*)d_in[4];
  const float* w_hi = (const float*)d_in[5];
  const float* b_hi = (const float*)d_in[6];
  const float* w_if = (const float*)d_in[7];
  const float* b_if = (const float*)d_in[8];
  const float* w_hf = (const float*)d_in[9];
  const float* b_hf = (const float*)d_in[10];
  const float* w_io = (const float*)d_in[11];
  const float* b_io = (const float*)d_in[12];
  const float* w_ho = (const float*)d_in[13];
  const float* b_ho = (const float*)d_in[14];
  const float* w_ig = (const float*)d_in[15];
  const float* b_ig = (const float*)d_in[16];
  const float* w_hg = (const float*)d_in[17];
  const float* b_hg = (const float*)d_in[18];

  unsigned short* xb = (unsigned short*)d_ws;          // 16777216 bf16
  unsigned short* wb = xb + 16777216;                  // 4*1048576 bf16
  float* hz = (float*)(wb + 4 * 1048576);              // 4*32*1024 f32
  float* out = (float*)d_out;

  hipLaunchKernelGGL(cvt_hz, dim3(3584), dim3(256), 0, stream,
                     x, w_ii, w_if, w_io, w_ig, xb, wb,
                     h0, w_hi, w_hf, w_ho, w_hg,
                     b_ii, b_hi, b_if, b_hf, b_io, b_ho, b_ig, b_hg, hz);
  hipLaunchKernelGGL(lstm_gemm8, dim3(256), dim3(512), 0, stream, xb, wb, hz, c0, out);
}

// Round 8
// 295.475 us; speedup vs baseline: 1.1863x; 1.1863x over previous
//
#include <hip/hip_runtime.h>
#include <hip/hip_bf16.h>

#define HSEQ 16777216   // 512*32*1024
#define NH 1024

typedef __attribute__((ext_vector_type(8))) short bf16x8;
typedef __attribute__((ext_vector_type(4))) float f32x4;

__device__ __forceinline__ unsigned short f2bf(float f) {
  unsigned u = __builtin_bit_cast(unsigned, f);
  u += 0x7fffu + ((u >> 16) & 1u);
  return (unsigned short)(u >> 16);
}

__device__ __forceinline__ float fsig(float z) {   // 1/(1+e^-z)
  float e = __builtin_amdgcn_exp2f(-1.442695041f * z);
  return __builtin_amdgcn_rcpf(1.f + e);
}
__device__ __forceinline__ float ftanh(float z) {  // 1 - 2/(e^{2z}+1)
  float e = __builtin_amdgcn_exp2f(2.885390082f * z);
  return 1.f - 2.f * __builtin_amdgcn_rcpf(1.f + e);
}

// Fused fp32->bf16 conversion: x (blocks 0-2047) + 4 gate weights (blocks 2048-3071).
__global__ __launch_bounds__(256) void cvt_all(
    const float* __restrict__ x,
    const float* __restrict__ wi, const float* __restrict__ wf,
    const float* __restrict__ wo, const float* __restrict__ wg,
    unsigned short* __restrict__ xb, unsigned short* __restrict__ wb) {
  int bid = blockIdx.x;
  const float* src; unsigned short* dst; int base, iters;
  if (bid < 2048) {
    src = x; dst = xb; base = bid * 8192; iters = 8;
  } else {
    int g = bid - 2048; int ws = g >> 8; int blk = g & 255;
    src = (ws == 0) ? wi : (ws == 1) ? wf : (ws == 2) ? wo : wg;
    dst = wb + ws * 1048576; base = blk * 4096; iters = 4;
  }
  int t = threadIdx.x;
  for (int i = 0; i < iters; ++i) {
    int idx = base + i * 1024 + t * 4;
    float4 v = *reinterpret_cast<const float4*>(src + idx);
    ushort4 o;
    o.x = f2bf(v.x); o.y = f2bf(v.y); o.z = f2bf(v.z); o.w = f2bf(v.w);
    *reinterpret_cast<ushort4*>(dst + idx) = o;
  }
}

// hz[g][b][h] = h0[b,:]·w_h[g][h,:] + b_i[g][h] + b_h[g][h]
__global__ __launch_bounds__(256) void hz_kernel(
    const float* __restrict__ h0,
    const float* __restrict__ wh_i, const float* __restrict__ wh_f,
    const float* __restrict__ wh_o, const float* __restrict__ wh_g,
    const float* __restrict__ bi_i, const float* __restrict__ bh_i,
    const float* __restrict__ bi_f, const float* __restrict__ bh_f,
    const float* __restrict__ bi_o, const float* __restrict__ bh_o,
    const float* __restrict__ bi_g, const float* __restrict__ bh_g,
    float* __restrict__ hz) {
  __shared__ float ws[8 * 1024];
  int g = blockIdx.x >> 7;
  int hb = blockIdx.x & 127;
  const float* wh = (g == 0) ? wh_i : (g == 1) ? wh_f : (g == 2) ? wh_o : wh_g;
  const float* bi = (g == 0) ? bi_i : (g == 1) ? bi_f : (g == 2) ? bi_o : bi_g;
  const float* bh = (g == 0) ? bh_i : (g == 1) ? bh_f : (g == 2) ? bh_o : bh_g;
  int tid = threadIdx.x;
  const float4* wsrc = reinterpret_cast<const float4*>(wh + hb * 8 * 1024);
  float4* wdst = reinterpret_cast<float4*>(ws);
  for (int i = tid; i < 2048; i += 256) wdst[i] = wsrc[i];
  __syncthreads();
  int b = tid & 31;
  int hh = tid >> 5;
  const float4* hv = reinterpret_cast<const float4*>(h0 + b * NH);
  const float4* wv = reinterpret_cast<const float4*>(ws + hh * NH);
  float acc = 0.f;
  for (int k = 0; k < 256; ++k) {
    float4 a = hv[k], w4 = wv[k];
    acc += a.x * w4.x + a.y * w4.y + a.z * w4.z + a.w * w4.w;
  }
  int h = hb * 8 + hh;
  hz[g * (32 * NH) + b * NH + h] = acc + bi[h] + bh[h];
}

__device__ __forceinline__ void load_lds16(const void* gsrc, void* lds) {
  __builtin_amdgcn_global_load_lds(
      (const __attribute__((address_space(1))) unsigned int*)gsrc,
      (__attribute__((address_space(3))) unsigned int*)lds, 16, 0, 0);
}

// Persistent 256x256 8-phase GEMM, grid=256, 1 block/CU, ONE dispatch round.
// Locality map: XCD x (= bid&7) exclusively owns m-tiles [8x,8x+8)
// (A/XCD = 4MB, L2-resident, fetched once). 32 blocks/XCD = 8 mtl x 4 hg;
// block's A-panel (mt) is FIXED; it cycles ht = hg + 4*pass, pass=0..3
// (concurrent B = 4 slices = 2MB, streamed once). K-sequence of 64 tiles
// (16 per pass) flows seamlessly; per-iter schedule byte-identical to the
// round-5 audited version (reg-double-buffered frags, 1 stage unit/phase,
// VM(4)@p2/p6, LGKM(4/8) counted).
__global__ __launch_bounds__(512, 2) void lstm_gemm8(
    const unsigned short* __restrict__ xb,   // [16384][1024] bf16
    const unsigned short* __restrict__ wb,   // [4][1024][1024] bf16 (i,f,o,g)
    const float* __restrict__ hz,            // [4][32][1024] f32
    const float* __restrict__ c0,            // [32][1024] f32
    float* __restrict__ out) {
  __shared__ unsigned short As[2][16384];    // [buf][256 rows][64 cols]
  __shared__ unsigned short Bs[2][16384];

  const int bid = blockIdx.x;                // 256 blocks
  const int xcd = bid & 7;
  const int local = bid >> 3;                // 0..31
  const int mtl = local & 7;
  const int hg = local >> 3;                 // 0..3
  const int mt = xcd * 8 + mtl;              // 0..63 (exclusive per XCD)
  const int b = mt >> 1;                     // batch, fixed per block

  const int tid = threadIdx.x;
  const int lane = tid & 63;
  const int w = tid >> 6;
  const int wr = w >> 2;        // 0..1
  const int wc = w & 3;         // 0..3
  const int laneLow = lane & 15;
  const int lane4 = lane >> 4;  // 0..3
  const int lx = lane & 7;

  const int sRow = w * 8 + (lane >> 3);               // row within 64-row round
  const int sCol = ((lane & 7) ^ (lane >> 3)) * 8;    // inverse-swizzled col
  const unsigned aOff = (unsigned)((mt * 256 + sRow) * 1024 + sCol);
  const unsigned bOffBase = (unsigned)((hg * 64 + sRow) * 1024 + sCol);

#define STAGE_A(buf, t, h)                                                         \
  do {                                                                             \
    _Pragma("unroll") for (int r_ = 0; r_ < 2; ++r_) {                             \
      load_lds16(xb + aOff + (unsigned)((((h) * 128 + r_ * 64) * 1024) +           \
                                        (((t) & 15) * 64)),                        \
                 &As[buf][(h) * 8192 + r_ * 4096 + w * 512]);                      \
    }                                                                              \
  } while (0)

#define STAGE_B(buf, t, h)                                                         \
  do {                                                                             \
    _Pragma("unroll") for (int r_ = 0; r_ < 2; ++r_) {                             \
      load_lds16(wb + (size_t)((h) * 2 + r_) * 1048576 + bOffBase +                \
                     (unsigned)((((t) >> 4) * 262144) + (((t) & 15) * 64)),        \
                 &Bs[buf][(h) * 8192 + r_ * 4096 + w * 512]);                      \
    }                                                                              \
  } while (0)

#define LDA(dst, buf, mh)                                                          \
  do {                                                                             \
    _Pragma("unroll") for (int mi = 0; mi < 4; ++mi)                               \
    _Pragma("unroll") for (int kk = 0; kk < 2; ++kk) {                             \
      int row_ = wr * 128 + (mh) * 64 + mi * 16 + laneLow;                         \
      int slot_ = (kk * 4 + lane4) ^ lx;                                           \
      dst[mi][kk] = *reinterpret_cast<const bf16x8*>(&As[buf][row_ * 64 + slot_ * 8]); \
    }                                                                              \
  } while (0)

#define LDB(dst, buf, qh)                                                          \
  do {                                                                             \
    _Pragma("unroll") for (int q = 0; q < 2; ++q)                                  \
    _Pragma("unroll") for (int kk = 0; kk < 2; ++kk) {                             \
      int row_ = ((qh) * 2 + q) * 64 + wc * 16 + laneLow;                          \
      int slot_ = (kk * 4 + lane4) ^ lx;                                           \
      dst[q][kk] = *reinterpret_cast<const bf16x8*>(&Bs[buf][row_ * 64 + slot_ * 8]); \
    }                                                                              \
  } while (0)

#define MFMA16(A, B, MH, QH)                                                       \
  do {                                                                             \
    __builtin_amdgcn_s_setprio(1);                                                 \
    _Pragma("unroll") for (int mi = 0; mi < 4; ++mi)                               \
    _Pragma("unroll") for (int q = 0; q < 2; ++q)                                  \
    _Pragma("unroll") for (int kk = 0; kk < 2; ++kk)                               \
      acc[(MH) * 4 + mi][(QH) * 2 + q] = __builtin_amdgcn_mfma_f32_16x16x32_bf16(  \
          A[mi][kk], B[q][kk], acc[(MH) * 4 + mi][(QH) * 2 + q], 0, 0, 0);         \
    __builtin_amdgcn_s_setprio(0);                                                 \
  } while (0)

#define BAR __builtin_amdgcn_s_barrier()
#define VM(n) asm volatile("s_waitcnt vmcnt(" #n ")" ::: "memory")

  f32x4 acc[8][4];
#pragma unroll
  for (int i = 0; i < 8; ++i)
#pragma unroll
    for (int jj = 0; jj < 4; ++jj) acc[i][jj] = (f32x4){0.f, 0.f, 0.f, 0.f};

  bf16x8 afX[4][2], afY[4][2], bqA[2][2], bqB[2][2];

  // Prologue: buf0 <- tile0 complete; buf1 <- tile1 (B0,B1,A0).
  STAGE_B(0, 0, 0); STAGE_B(0, 0, 1); STAGE_A(0, 0, 0); STAGE_A(0, 0, 1);
  STAGE_B(1, 1, 0); STAGE_B(1, 1, 1); STAGE_A(1, 1, 0);
  VM(0);
  BAR;
  LDB(bqA, 0, 0);
  LDA(afX, 0, 0);

  for (int pass = 0; pass < 4; ++pass) {     // ht = hg + 4*pass
#pragma unroll
    for (int it2 = 0; it2 < 8; ++it2) {
      const int base_t = 16 * pass + 2 * it2;
      const int tOdd = base_t + 1;
      const int tA2 = (base_t + 2 > 63) ? 63 : base_t + 2;
      const int tB2 = (base_t + 3 > 63) ? 63 : base_t + 3;

      // p0
      LDB(bqB, 0, 1);
      STAGE_A(1, tOdd, 1);
      MFMA16(afX, bqA, 0, 0);
      BAR;
      // p1
      LDA(afY, 0, 1);
      STAGE_B(0, tA2, 0);
      MFMA16(afX, bqB, 0, 1);
      BAR;
      // p2
      STAGE_B(0, tA2, 1);
      MFMA16(afY, bqB, 1, 1);
      VM(4);
      BAR;
      // p3
      LDB(bqB, 1, 0);
      LDA(afX, 1, 0);
      STAGE_A(0, tA2, 0);
      MFMA16(afY, bqA, 1, 0);
      BAR;
      // p4
      LDB(bqA, 1, 1);
      STAGE_A(0, tA2, 1);
      MFMA16(afX, bqB, 0, 0);
      BAR;
      // p5
      LDA(afY, 1, 1);
      STAGE_B(1, tB2, 0);
      MFMA16(afX, bqA, 0, 1);
      BAR;
      // p6
      STAGE_B(1, tB2, 1);
      MFMA16(afY, bqA, 1, 1);
      VM(4);
      BAR;
      // p7
      LDB(bqA, 0, 0);
      LDA(afX, 0, 0);
      STAGE_A(1, tB2, 0);
      MFMA16(afY, bqB, 1, 0);
      BAR;
    }

    // ---- epilogue for pass (register-only math + stores; no barrier) ----
    {
      const int hOut = (hg + 4 * pass) * 64 + wc * 16 + laneLow;
      const float hz0 = hz[0 * 32768 + b * 1024 + hOut];
      const float hz1 = hz[1 * 32768 + b * 1024 + hOut];
      const float hz2 = hz[2 * 32768 + b * 1024 + hOut];
      const float hz3 = hz[3 * 32768 + b * 1024 + hOut];
      const float c0v = c0[b * 1024 + hOut];
      const int mB = mt * 256;
#pragma unroll
      for (int mi16 = 0; mi16 < 8; ++mi16) {
#pragma unroll
        for (int r = 0; r < 4; ++r) {
          int m = mB + wr * 128 + mi16 * 16 + lane4 * 4 + r;
          int ts = m & 511;
          float zi = acc[mi16][0][r] + hz0;
          float zf = acc[mi16][1][r] + hz1;
          float zo = acc[mi16][2][r] + hz2;
          float zg = acc[mi16][3][r] + hz3;
          float iv = fsig(zi);
          float fv = fsig(zf);
          float ov = fsig(zo);
          float gv = ftanh(zg);
          float cv = fv * c0v + iv * gv;
          float hval = ov * ftanh(cv);
          out[(size_t)ts * 32768 + b * 1024 + hOut] = hval;
          if (ts == 511) {
            out[HSEQ + b * 1024 + hOut] = hval;
            out[HSEQ + 32768 + b * 1024 + hOut] = cv;
          }
        }
      }
#pragma unroll
      for (int i = 0; i < 8; ++i)
#pragma unroll
        for (int jj = 0; jj < 4; ++jj) acc[i][jj] = (f32x4){0.f, 0.f, 0.f, 0.f};
    }
  }
}

extern "C" void kernel_launch(void* const* d_in, const int* in_sizes, int n_in,
                              void* d_out, int out_size, void* d_ws, size_t ws_size,
                              hipStream_t stream) {
  const float* x    = (const float*)d_in[0];
  const float* h0   = (const float*)d_in[1];
  const float* c0   = (const float*)d_in[2];
  const float* w_ii = (const float*)d_in[3];
  const float* b_ii = (const float*)d_in[4];
  const float* w_hi = (const float*)d_in[5];
  const float* b_hi = (const float*)d_in[6];
  const float* w_if = (const float*)d_in[7];
  const float* b_if = (const float*)d_in[8];
  const float* w_hf = (const float*)d_in[9];
  const float* b_hf = (const float*)d_in[10];
  const float* w_io = (const float*)d_in[11];
  const float* b_io = (const float*)d_in[12];
  const float* w_ho = (const float*)d_in[13];
  const float* b_ho = (const float*)d_in[14];
  const float* w_ig = (const float*)d_in[15];
  const float* b_ig = (const float*)d_in[16];
  const float* w_hg = (const float*)d_in[17];
  const float* b_hg = (const float*)d_in[18];

  unsigned short* xb = (unsigned short*)d_ws;          // 16777216 bf16
  unsigned short* wb = xb + 16777216;                  // 4*1048576 bf16
  float* hz = (float*)(wb + 4 * 1048576);              // 4*32*1024 f32
  float* out = (float*)d_out;

  hipLaunchKernelGGL(cvt_all, dim3(3072), dim3(256), 0, stream,
                     x, w_ii, w_if, w_io, w_ig, xb, wb);
  hipLaunchKernelGGL(hz_kernel, dim3(512), dim3(256), 0, stream, h0,
                     w_hi, w_hf, w_ho, w_hg,
                     b_ii, b_hi, b_if, b_hf, b_io, b_ho, b_ig, b_hg, hz);
  hipLaunchKernelGGL(lstm_gemm8, dim3(256), dim3(512), 0, stream, xb, wb, hz, c0, out);
}

// Round 9
// 220.971 us; speedup vs baseline: 1.5863x; 1.3372x over previous
//
#include <hip/hip_runtime.h>
#include <hip/hip_bf16.h>

#define HSEQ 16777216   // 512*32*1024
#define NH 1024

typedef __attribute__((ext_vector_type(8))) short bf16x8;
typedef __attribute__((ext_vector_type(4))) float f32x4;

__device__ __forceinline__ unsigned short f2bf(float f) {
  unsigned u = __builtin_bit_cast(unsigned, f);
  u += 0x7fffu + ((u >> 16) & 1u);
  return (unsigned short)(u >> 16);
}

__device__ __forceinline__ float fsig(float z) {   // 1/(1+e^-z)
  float e = __builtin_amdgcn_exp2f(-1.442695041f * z);
  return __builtin_amdgcn_rcpf(1.f + e);
}
__device__ __forceinline__ float ftanh(float z) {  // 1 - 2/(e^{2z}+1)
  float e = __builtin_amdgcn_exp2f(2.885390082f * z);
  return 1.f - 2.f * __builtin_amdgcn_rcpf(1.f + e);
}

// Fused fp32->bf16 conversion: x (blocks 0-2047) + 4 gate weights (blocks 2048-3071).
__global__ __launch_bounds__(256) void cvt_all(
    const float* __restrict__ x,
    const float* __restrict__ wi, const float* __restrict__ wf,
    const float* __restrict__ wo, const float* __restrict__ wg,
    unsigned short* __restrict__ xb, unsigned short* __restrict__ wb) {
  int bid = blockIdx.x;
  const float* src; unsigned short* dst; int base, iters;
  if (bid < 2048) {
    src = x; dst = xb; base = bid * 8192; iters = 8;
  } else {
    int g = bid - 2048; int ws = g >> 8; int blk = g & 255;
    src = (ws == 0) ? wi : (ws == 1) ? wf : (ws == 2) ? wo : wg;
    dst = wb + ws * 1048576; base = blk * 4096; iters = 4;
  }
  int t = threadIdx.x;
  for (int i = 0; i < iters; ++i) {
    int idx = base + i * 1024 + t * 4;
    float4 v = *reinterpret_cast<const float4*>(src + idx);
    ushort4 o;
    o.x = f2bf(v.x); o.y = f2bf(v.y); o.z = f2bf(v.z); o.w = f2bf(v.w);
    *reinterpret_cast<ushort4*>(dst + idx) = o;
  }
}

// hz[g][b][h] = h0[b,:]·w_h[g][h,:] + b_i[g][h] + b_h[g][h]
__global__ __launch_bounds__(256) void hz_kernel(
    const float* __restrict__ h0,
    const float* __restrict__ wh_i, const float* __restrict__ wh_f,
    const float* __restrict__ wh_o, const float* __restrict__ wh_g,
    const float* __restrict__ bi_i, const float* __restrict__ bh_i,
    const float* __restrict__ bi_f, const float* __restrict__ bh_f,
    const float* __restrict__ bi_o, const float* __restrict__ bh_o,
    const float* __restrict__ bi_g, const float* __restrict__ bh_g,
    float* __restrict__ hz) {
  __shared__ float ws[8 * 1024];
  int g = blockIdx.x >> 7;
  int hb = blockIdx.x & 127;
  const float* wh = (g == 0) ? wh_i : (g == 1) ? wh_f : (g == 2) ? wh_o : wh_g;
  const float* bi = (g == 0) ? bi_i : (g == 1) ? bi_f : (g == 2) ? bi_o : bi_g;
  const float* bh = (g == 0) ? bh_i : (g == 1) ? bh_f : (g == 2) ? bh_o : bh_g;
  int tid = threadIdx.x;
  const float4* wsrc = reinterpret_cast<const float4*>(wh + hb * 8 * 1024);
  float4* wdst = reinterpret_cast<float4*>(ws);
  for (int i = tid; i < 2048; i += 256) wdst[i] = wsrc[i];
  __syncthreads();
  int b = tid & 31;
  int hh = tid >> 5;
  const float4* hv = reinterpret_cast<const float4*>(h0 + b * NH);
  const float4* wv = reinterpret_cast<const float4*>(ws + hh * NH);
  float acc = 0.f;
  for (int k = 0; k < 256; ++k) {
    float4 a = hv[k], w4 = wv[k];
    acc += a.x * w4.x + a.y * w4.y + a.z * w4.z + a.w * w4.w;
  }
  int h = hb * 8 + hh;
  hz[g * (32 * NH) + b * NH + h] = acc + bi[h] + bh[h];
}

__device__ __forceinline__ void load_lds16(const void* gsrc, void* lds) {
  __builtin_amdgcn_global_load_lds(
      (const __attribute__((address_space(1))) unsigned int*)gsrc,
      (__attribute__((address_space(3))) unsigned int*)lds, 16, 0, 0);
}

// 128 x (4g x 32h) tile, BK=64, single-buffered LDS (32KB), 4 waves, TLP-first:
// __launch_bounds__(256,4) targets 4 blocks/CU so co-resident blocks hide the
// stage latency (R2 mechanism). T2 XOR swizzle on LDS (verified R5 formulas)
// keeps ds_read_b128 conflict-free at the 128B row stride. XCD swizzle gives
// each XCD a disjoint 16-mt A-range (hot set ~1MB A + ~2MB B window -> L2-hit
// staging).
__global__ __launch_bounds__(256, 4) void lstm_gemm(
    const unsigned short* __restrict__ xb,   // [16384][1024] bf16
    const unsigned short* __restrict__ wb,   // [4][1024][1024] bf16 (i,f,o,g)
    const float* __restrict__ hz,            // [4][32][1024] f32
    const float* __restrict__ c0,            // [32][1024] f32
    float* __restrict__ out) {
  __shared__ unsigned short As[128 * 64];    // 16 KB
  __shared__ unsigned short Bs[128 * 64];    // 16 KB

  const int orig = blockIdx.x;               // 4096 blocks, 4096%8==0
  const int bid = (orig & 7) * 512 + (orig >> 3);   // XCD swizzle
  const int mt = bid >> 5;                   // 0..127 (disjoint 16-mt range/XCD)
  const int ht = bid & 31;                   // 0..31
  const int mBase = mt * 128;
  const int hBase = ht * 32;

  const int tid = threadIdx.x;
  const int lane = tid & 63;
  const int w = tid >> 6;                    // 0..3
  const int laneLow = lane & 15;
  const int lane4 = lane >> 4;               // 0..3

  // staging geometry: unit = 8 rows x 64 cols (1KB); lane covers row sR, 16B
  const int sR = lane >> 3;                  // 0..7
  const int sL = ((lane & 7) ^ sR) * 8;      // inverse-swizzled logical col

  f32x4 acc[2][8];
#pragma unroll
  for (int i = 0; i < 2; ++i)
#pragma unroll
    for (int j = 0; j < 8; ++j) acc[i][j] = (f32x4){0.f, 0.f, 0.f, 0.f};

  for (int kt = 0; kt < 16; ++kt) {
    const int k0 = kt * 64;
    // stage A: 16 units, wave w does units j*4+w
#pragma unroll
    for (int j = 0; j < 4; ++j) {
      int c = j * 4 + w;
      int row = c * 8 + sR;
      load_lds16(xb + (size_t)(mBase + row) * 1024 + k0 + sL, As + c * 512);
    }
    // stage B (eff-N rows: n = gate*32 + hh)
#pragma unroll
    for (int j = 0; j < 4; ++j) {
      int c = j * 4 + w;
      int n = c * 8 + sR;
      int gate = n >> 5, hh = n & 31;
      load_lds16(wb + (size_t)gate * 1048576 + (size_t)(hBase + hh) * 1024 + k0 + sL,
                 Bs + c * 512);
    }
    asm volatile("s_waitcnt vmcnt(0)" ::: "memory");
    __builtin_amdgcn_s_barrier();

    bf16x8 af[2][2];
#pragma unroll
    for (int mi = 0; mi < 2; ++mi)
#pragma unroll
      for (int kk = 0; kk < 2; ++kk) {
        int row = w * 32 + mi * 16 + laneLow;
        int slot = (kk * 4 + lane4) ^ (laneLow & 7);
        af[mi][kk] = *reinterpret_cast<const bf16x8*>(&As[row * 64 + slot * 8]);
      }
#pragma unroll
    for (int nf = 0; nf < 8; ++nf) {
      bf16x8 bfb0, bfb1;
      {
        int n = nf * 16 + laneLow;
        int slot0 = (0 * 4 + lane4) ^ (laneLow & 7);
        int slot1 = (1 * 4 + lane4) ^ (laneLow & 7);
        bfb0 = *reinterpret_cast<const bf16x8*>(&Bs[n * 64 + slot0 * 8]);
        bfb1 = *reinterpret_cast<const bf16x8*>(&Bs[n * 64 + slot1 * 8]);
      }
      acc[0][nf] = __builtin_amdgcn_mfma_f32_16x16x32_bf16(af[0][0], bfb0, acc[0][nf], 0, 0, 0);
      acc[1][nf] = __builtin_amdgcn_mfma_f32_16x16x32_bf16(af[1][0], bfb0, acc[1][nf], 0, 0, 0);
      acc[0][nf] = __builtin_amdgcn_mfma_f32_16x16x32_bf16(af[0][1], bfb1, acc[0][nf], 0, 0, 0);
      acc[1][nf] = __builtin_amdgcn_mfma_f32_16x16x32_bf16(af[1][1], bfb1, acc[1][nf], 0, 0, 0);
    }
    __builtin_amdgcn_s_barrier();
  }

  // epilogue: combine gates (R2-verified layout), cheap activations, f32 writes
  const int b = mBase >> 9;  // uniform per block (128 | 512)
#pragma unroll
  for (int mi = 0; mi < 2; ++mi) {
#pragma unroll
    for (int n16 = 0; n16 < 2; ++n16) {
      int h = hBase + n16 * 16 + laneLow;
      float hz_i = hz[0 * 32768 + b * NH + h];
      float hz_f = hz[1 * 32768 + b * NH + h];
      float hz_o = hz[2 * 32768 + b * NH + h];
      float hz_g = hz[3 * 32768 + b * NH + h];
      float c0v = c0[b * NH + h];
#pragma unroll
      for (int r = 0; r < 4; ++r) {
        int row = w * 32 + mi * 16 + lane4 * 4 + r;
        int m = mBase + row;
        int t = m & 511;
        float zi = acc[mi][0 + n16][r] + hz_i;
        float zf = acc[mi][2 + n16][r] + hz_f;
        float zo = acc[mi][4 + n16][r] + hz_o;
        float zg = acc[mi][6 + n16][r] + hz_g;
        float iv = fsig(zi);
        float fv = fsig(zf);
        float ov = fsig(zo);
        float gv = ftanh(zg);
        float cv = fv * c0v + iv * gv;
        float hval = ov * ftanh(cv);
        out[((size_t)t * 32 + b) * 1024 + h] = hval;
        if (t == 511) {
          out[HSEQ + b * NH + h] = hval;
          out[HSEQ + 32768 + b * NH + h] = cv;
        }
      }
    }
  }
}

extern "C" void kernel_launch(void* const* d_in, const int* in_sizes, int n_in,
                              void* d_out, int out_size, void* d_ws, size_t ws_size,
                              hipStream_t stream) {
  const float* x    = (const float*)d_in[0];
  const float* h0   = (const float*)d_in[1];
  const float* c0   = (const float*)d_in[2];
  const float* w_ii = (const float*)d_in[3];
  const float* b_ii = (const float*)d_in[4];
  const float* w_hi = (const float*)d_in[5];
  const float* b_hi = (const float*)d_in[6];
  const float* w_if = (const float*)d_in[7];
  const float* b_if = (const float*)d_in[8];
  const float* w_hf = (const float*)d_in[9];
  const float* b_hf = (const float*)d_in[10];
  const float* w_io = (const float*)d_in[11];
  const float* b_io = (const float*)d_in[12];
  const float* w_ho = (const float*)d_in[13];
  const float* b_ho = (const float*)d_in[14];
  const float* w_ig = (const float*)d_in[15];
  const float* b_ig = (const float*)d_in[16];
  const float* w_hg = (const float*)d_in[17];
  const float* b_hg = (const float*)d_in[18];

  unsigned short* xb = (unsigned short*)d_ws;          // 16777216 bf16
  unsigned short* wb = xb + 16777216;                  // 4*1048576 bf16
  float* hz = (float*)(wb + 4 * 1048576);              // 4*32*1024 f32
  float* out = (float*)d_out;

  hipLaunchKernelGGL(cvt_all, dim3(3072), dim3(256), 0, stream,
                     x, w_ii, w_if, w_io, w_ig, xb, wb);
  hipLaunchKernelGGL(hz_kernel, dim3(512), dim3(256), 0, stream, h0,
                     w_hi, w_hf, w_ho, w_hg,
                     b_ii, b_hi, b_if, b_hf, b_io, b_ho, b_ig, b_hg, hz);
  hipLaunchKernelGGL(lstm_gemm, dim3(4096), dim3(256), 0, stream, xb, wb, hz, c0, out);
}